// Round 1
// baseline (1224.316 us; speedup 1.0000x reference)
//
#include <hip/hip_runtime.h>

// Problem constants (from reference): obj (3,2160,3840) f32, flow (2,H,W) f32,
// depth (1,H,W) f32. Outputs concat: out (3,H,W), valid (1,H,W), collision (1,H,W).
#define CH 3
#define HH 2160
#define WW 3840
#define HWN (HH * WW)

// Monotonic float <-> uint mapping (order-preserving for all non-NaN floats).
__device__ __forceinline__ unsigned fmap(float f) {
    unsigned u = __float_as_uint(f);
    return (u & 0x80000000u) ? ~u : (u | 0x80000000u);
}
__device__ __forceinline__ float funmap(unsigned u) {
    return __uint_as_float((u & 0x80000000u) ? (u ^ 0x80000000u) : ~u);
}

// Kernel 1: zero all of d_out (5*HW uints) and set min-depth ws to 0xFFFFFFFF.
__global__ void k_init(unsigned* __restrict__ out, unsigned* __restrict__ mind) {
    int stride = gridDim.x * blockDim.x;
    int i0 = blockIdx.x * blockDim.x + threadIdx.x;
    for (long p = i0; p < 5L * HWN; p += stride) out[p] = 0u;
    for (int p = i0; p < HWN; p += stride) mind[p] = 0xFFFFFFFFu;
}

__device__ __forceinline__ int target_idx(int p, const float* __restrict__ flow) {
    int y = p / WW;
    int x = p - y * WW;
    float tx = (float)x + flow[p];
    float ty = (float)y + flow[HWN + p];
    tx = fminf(fmaxf(tx, 0.0f), (float)(WW - 1));
    ty = fminf(fmaxf(ty, 0.0f), (float)(HH - 1));
    int xi = (int)tx;   // truncation (>=0 so floor), matches astype(int32)
    int yi = (int)ty;
    return yi * WW + xi;
}

// Kernel 2: count + z-buffer min depth.
__global__ void k_pass1(const float* __restrict__ flow, const float* __restrict__ depth,
                        unsigned* __restrict__ cnt, unsigned* __restrict__ mind) {
    int p = blockIdx.x * blockDim.x + threadIdx.x;
    if (p >= HWN) return;
    int idx = target_idx(p, flow);
    atomicAdd(&cnt[idx], 1u);
    // depth strictly positive -> uint bit pattern is order-isomorphic
    atomicMin(&mind[idx], __float_as_uint(depth[p]));
}

// Kernel 3: winners scatter per-channel max of obj.
__global__ void k_pass2(const float* __restrict__ obj, const float* __restrict__ flow,
                        const float* __restrict__ depth, const unsigned* __restrict__ mind,
                        unsigned* __restrict__ acc) {
    int p = blockIdx.x * blockDim.x + threadIdx.x;
    if (p >= HWN) return;
    int idx = target_idx(p, flow);
    unsigned db = __float_as_uint(depth[p]);
    if (db <= mind[idx]) {          // d <= min_d  (ties -> multiple winners, like ref)
        atomicMax(&acc[idx],            fmap(obj[p]));
        atomicMax(&acc[HWN + idx],      fmap(obj[HWN + p]));
        atomicMax(&acc[2 * HWN + idx],  fmap(obj[2 * HWN + p]));
    }
}

// Kernel 4: finalize in place. Layout in d_out: [0,3HW) out-acc, [3HW,4HW) valid,
// [4HW,5HW) collision count (uint).
__global__ void k_final(unsigned* __restrict__ u, float* __restrict__ f) {
    int p = blockIdx.x * blockDim.x + threadIdx.x;
    if (p >= HWN) return;
    unsigned cu = u[4 * HWN + p];
    f[4 * HWN + p] = (float)cu;              // counts < 2^24 -> exact
    f[3 * HWN + p] = (cu > 0u) ? 1.0f : 0.0f;
    if (cu > 0u) {
        f[p]           = funmap(u[p]);
        f[HWN + p]     = funmap(u[HWN + p]);
        f[2 * HWN + p] = funmap(u[2 * HWN + p]);
    } else {
        f[p] = 0.0f;
        f[HWN + p] = 0.0f;
        f[2 * HWN + p] = 0.0f;
    }
}

extern "C" void kernel_launch(void* const* d_in, const int* in_sizes, int n_in,
                              void* d_out, int out_size, void* d_ws, size_t ws_size,
                              hipStream_t stream) {
    const float* obj   = (const float*)d_in[0];
    const float* flow  = (const float*)d_in[1];
    const float* depth = (const float*)d_in[2];
    unsigned* outu = (unsigned*)d_out;
    float*    outf = (float*)d_out;
    unsigned* mind = (unsigned*)d_ws;   // HW * 4 bytes = 33.2 MB

    const int T = 256;
    const int gridHW = (HWN + T - 1) / T;   // 32400 blocks

    k_init <<<4096, T, 0, stream>>>(outu, mind);
    k_pass1<<<gridHW, T, 0, stream>>>(flow, depth, outu + 4L * HWN, mind);
    k_pass2<<<gridHW, T, 0, stream>>>(obj, flow, depth, mind, outu);
    k_final<<<gridHW, T, 0, stream>>>(outu, outf);
}

// Round 2
// 477.853 us; speedup vs baseline: 2.5621x; 2.5621x over previous
//
#include <hip/hip_runtime.h>

// obj (3,2160,3840) f32, flow (2,H,W) f32, depth (1,H,W) f32.
// Outputs concat: out (3,H,W), valid (1,H,W), collision (1,H,W)  => 5*HW floats.
#define CH 3
#define HH 2160
#define WW 3840
#define HWN (HH * WW)

// ---- tiled-gather parameters ----
#define TDX 128                 // tile width
#define TDY 48                  // tile height
#define WIN 64                  // source-window margin (perf-only; fallback handles beyond)
#define SCX (TDX + 2 * WIN)     // 256
#define SCY (TDY + 2 * WIN)     // 176
#define NTX (WW / TDX)          // 30
#define NTY (HH / TDY)          // 45
#define TPX (TDX * TDY)         // 6144 pixels per tile
#define NTHREADS 1024

__device__ __forceinline__ void target_of(int sx, int sy, float fx, float fy,
                                          int& tx, int& ty) {
    float txf = fminf(fmaxf((float)sx + fx, 0.0f), (float)(WW - 1));
    float tyf = fminf(fmaxf((float)sy + fy, 0.0f), (float)(HH - 1));
    tx = (int)txf;   // >=0 -> truncation == floor, matches astype(int32)
    ty = (int)tyf;
}

// ---------------- tiled path ----------------

// Init fallback accumulators: keys to all-ones (max), counts to 0.
__global__ void k_init_fb(unsigned long long* __restrict__ fbA,
                          unsigned long long* __restrict__ fbB,
                          unsigned* __restrict__ fbc) {
    int stride = gridDim.x * blockDim.x;
    for (int i = blockIdx.x * blockDim.x + threadIdx.x; i < HWN; i += stride) {
        fbA[i] = ~0ULL;
        fbB[i] = ~0ULL;
        fbc[i] = 0u;
    }
}

// Fallback scatter: sources whose target's owning tile does NOT scan them.
__global__ void k_fb(const float* __restrict__ flow, const float* __restrict__ depth,
                     unsigned long long* __restrict__ fbA,
                     unsigned long long* __restrict__ fbB,
                     unsigned* __restrict__ fbc) {
    int p = blockIdx.x * blockDim.x + threadIdx.x;
    if (p >= HWN) return;
    int sy = p / WW;
    int sx = p - sy * WW;
    float fx = flow[p], fy = flow[HWN + p];
    int tx, ty;
    target_of(sx, sy, fx, fy, tx, ty);
    int x0 = (tx / TDX) * TDX;
    int y0 = (ty / TDY) * TDY;
    bool in_region = (sx >= x0 - WIN) && (sx < x0 + TDX + WIN) &&
                     (sy >= y0 - WIN) && (sy < y0 + TDY + WIN);
    if (in_region) return;                    // owning tile will scan this source
    int idx = ty * WW + tx;
    unsigned db = __float_as_uint(depth[p]);  // depth > 0 -> bits order-isomorphic
    unsigned long long kA = ((unsigned long long)db << 32) | (unsigned)p;
    unsigned long long kB = ((unsigned long long)db << 32) | (unsigned)(~p);
    atomicAdd(&fbc[idx], 1u);
    atomicMin(&fbA[idx], kA);
    atomicMin(&fbB[idx], kB);
}

// Main: per target tile, LDS z-buffer over the source window, then gather.
__global__ __launch_bounds__(NTHREADS) void k_main(
    const float* __restrict__ obj, const float* __restrict__ flow,
    const float* __restrict__ depth,
    const unsigned long long* __restrict__ fbA,
    const unsigned long long* __restrict__ fbB,
    const unsigned* __restrict__ fbc,
    float* __restrict__ outf) {
    __shared__ unsigned long long A[TPX];   // min (depth_bits, src_id)
    __shared__ unsigned long long B[TPX];   // min (depth_bits, ~src_id)
    __shared__ unsigned cnt[TPX];           // 6144*(8+8+4) = 120 KiB LDS

    int tix = blockIdx.x % NTX;
    int tiy = blockIdx.x / NTX;
    int x0 = tix * TDX;
    int y0 = tiy * TDY;

    for (int i = threadIdx.x; i < TPX; i += NTHREADS) {
        A[i] = ~0ULL;
        B[i] = ~0ULL;
        cnt[i] = 0u;
    }
    __syncthreads();

    // Scan source window (tile +- WIN), clipped to the image.
    for (int t = threadIdx.x; t < SCX * SCY; t += NTHREADS) {
        int wx = t % SCX;          // == threadIdx.x % 256 -> coalesced rows
        int wy = t / SCX;
        int sx = x0 - WIN + wx;
        int sy = y0 - WIN + wy;
        if (sx < 0 || sx >= WW || sy < 0 || sy >= HH) continue;
        int p = sy * WW + sx;
        float fx = flow[p], fy = flow[HWN + p];
        int tx, ty;
        target_of(sx, sy, fx, fy, tx, ty);
        if (tx < x0 || tx >= x0 + TDX || ty < y0 || ty >= y0 + TDY) continue;
        int li = (ty - y0) * TDX + (tx - x0);
        unsigned db = __float_as_uint(depth[p]);
        unsigned long long kA = ((unsigned long long)db << 32) | (unsigned)p;
        unsigned long long kB = ((unsigned long long)db << 32) | (unsigned)(~p);
        atomicAdd(&cnt[li], 1u);
        atomicMin(&A[li], kA);
        atomicMin(&B[li], kB);
    }
    __syncthreads();

    // Finalize: merge fallback, gather winner obj, write all 5 planes.
    for (int i = threadIdx.x; i < TPX; i += NTHREADS) {
        int lx = i % TDX;
        int ly = i / TDX;
        int g = (y0 + ly) * WW + (x0 + lx);
        unsigned long long a = A[i];
        unsigned long long fa = fbA[g];
        if (fa < a) a = fa;
        unsigned long long b = B[i];
        unsigned long long fb = fbB[g];
        if (fb < b) b = fb;
        unsigned c = cnt[i] + fbc[g];
        float o0 = 0.0f, o1 = 0.0f, o2 = 0.0f, v = 0.0f;
        if (c > 0u) {
            v = 1.0f;
            unsigned idA = (unsigned)a;        // smallest id at min depth
            unsigned idB = ~(unsigned)b;       // largest id at min depth
            o0 = obj[idA];
            o1 = obj[HWN + idA];
            o2 = obj[2 * HWN + idA];
            if (idB != idA) {                  // exact-depth tie: ref takes max obj
                o0 = fmaxf(o0, obj[idB]);
                o1 = fmaxf(o1, obj[HWN + idB]);
                o2 = fmaxf(o2, obj[2 * HWN + idB]);
            }
        }
        outf[g] = o0;
        outf[HWN + g] = o1;
        outf[2 * HWN + g] = o2;
        outf[3 * HWN + g] = v;
        outf[4 * HWN + g] = (float)c;
    }
}

// ---------------- fallback (Round-0, proven) path ----------------

__device__ __forceinline__ unsigned fmap(float f) {
    unsigned u = __float_as_uint(f);
    return (u & 0x80000000u) ? ~u : (u | 0x80000000u);
}
__device__ __forceinline__ float funmap(unsigned u) {
    return __uint_as_float((u & 0x80000000u) ? (u ^ 0x80000000u) : ~u);
}

__global__ void k_init(unsigned* __restrict__ out, unsigned* __restrict__ mind) {
    int stride = gridDim.x * blockDim.x;
    int i0 = blockIdx.x * blockDim.x + threadIdx.x;
    for (long p = i0; p < 5L * HWN; p += stride) out[p] = 0u;
    for (int p = i0; p < HWN; p += stride) mind[p] = 0xFFFFFFFFu;
}

__device__ __forceinline__ int target_idx(int p, const float* __restrict__ flow) {
    int y = p / WW;
    int x = p - y * WW;
    int tx, ty;
    target_of(x, y, flow[p], flow[HWN + p], tx, ty);
    return ty * WW + tx;
}

__global__ void k_pass1(const float* __restrict__ flow, const float* __restrict__ depth,
                        unsigned* __restrict__ cnt, unsigned* __restrict__ mind) {
    int p = blockIdx.x * blockDim.x + threadIdx.x;
    if (p >= HWN) return;
    int idx = target_idx(p, flow);
    atomicAdd(&cnt[idx], 1u);
    atomicMin(&mind[idx], __float_as_uint(depth[p]));
}

__global__ void k_pass2(const float* __restrict__ obj, const float* __restrict__ flow,
                        const float* __restrict__ depth, const unsigned* __restrict__ mind,
                        unsigned* __restrict__ acc) {
    int p = blockIdx.x * blockDim.x + threadIdx.x;
    if (p >= HWN) return;
    int idx = target_idx(p, flow);
    unsigned db = __float_as_uint(depth[p]);
    if (db <= mind[idx]) {
        atomicMax(&acc[idx], fmap(obj[p]));
        atomicMax(&acc[HWN + idx], fmap(obj[HWN + p]));
        atomicMax(&acc[2 * HWN + idx], fmap(obj[2 * HWN + p]));
    }
}

__global__ void k_final(unsigned* __restrict__ u, float* __restrict__ f) {
    int p = blockIdx.x * blockDim.x + threadIdx.x;
    if (p >= HWN) return;
    unsigned cu = u[4 * HWN + p];
    f[4 * HWN + p] = (float)cu;
    f[3 * HWN + p] = (cu > 0u) ? 1.0f : 0.0f;
    if (cu > 0u) {
        f[p] = funmap(u[p]);
        f[HWN + p] = funmap(u[HWN + p]);
        f[2 * HWN + p] = funmap(u[2 * HWN + p]);
    } else {
        f[p] = 0.0f;
        f[HWN + p] = 0.0f;
        f[2 * HWN + p] = 0.0f;
    }
}

extern "C" void kernel_launch(void* const* d_in, const int* in_sizes, int n_in,
                              void* d_out, int out_size, void* d_ws, size_t ws_size,
                              hipStream_t stream) {
    const float* obj   = (const float*)d_in[0];
    const float* flow  = (const float*)d_in[1];
    const float* depth = (const float*)d_in[2];
    float* outf = (float*)d_out;

    const int T = 256;
    const int gridHW = (HWN + T - 1) / T;

    const size_t needWS = (size_t)HWN * 20u;  // fbA(8) + fbB(8) + fbc(4) = 165,888,000 B

    if (ws_size >= needWS) {
        unsigned long long* fbA = (unsigned long long*)d_ws;
        unsigned long long* fbB = fbA + HWN;
        unsigned* fbc = (unsigned*)(fbB + HWN);

        k_init_fb<<<2048, 256, 0, stream>>>(fbA, fbB, fbc);
        k_fb<<<gridHW, T, 0, stream>>>(flow, depth, fbA, fbB, fbc);
        k_main<<<NTX * NTY, NTHREADS, 0, stream>>>(obj, flow, depth, fbA, fbB, fbc, outf);
    } else {
        unsigned* outu = (unsigned*)d_out;
        unsigned* mind = (unsigned*)d_ws;  // 33.2 MB
        k_init<<<4096, T, 0, stream>>>(outu, mind);
        k_pass1<<<gridHW, T, 0, stream>>>(flow, depth, outu + 4L * HWN, mind);
        k_pass2<<<gridHW, T, 0, stream>>>(obj, flow, depth, mind, outu);
        k_final<<<gridHW, T, 0, stream>>>(outu, outf);
    }
}

// Round 3
// 342.458 us; speedup vs baseline: 3.5751x; 1.3954x over previous
//
#include <hip/hip_runtime.h>

typedef unsigned long long u64;

// obj (3,2160,3840) f32, flow (2,H,W) f32, depth (1,H,W) f32.
// Outputs concat: out (3,H,W), valid (1,H,W), collision (1,H,W) => 5*HW floats.
#define HH 2160
#define WW 3840
#define HWN (HH * WW)            // 8,294,400

// ---- exact binning geometry ----
#define TDX 128
#define TDY 27
#define NTX (WW / TDX)           // 30
#define NTY (HH / TDY)           // 80
#define NTILES (NTX * NTY)       // 2400
#define TPX (TDX * TDY)          // 3456  -> LDS 3456*(8+8+4) = 67.5 KiB (2 blocks/CU)

#define SLAB 4096
#define NSLABS (HWN / SLAB)      // 2025 exactly (2025*4096 == HWN)
#define SCHUNK 10                // ceil(2400/256)

__device__ __forceinline__ void target_of(int sx, int sy, float fx, float fy,
                                          int& tx, int& ty) {
    float txf = fminf(fmaxf((float)sx + fx, 0.0f), (float)(WW - 1));
    float tyf = fminf(fmaxf((float)sy + fy, 0.0f), (float)(HH - 1));
    tx = (int)txf;   // >=0 -> truncation == floor, matches astype(int32)
    ty = (int)tyf;
}

__device__ __forceinline__ int tile_of(int p, const float* __restrict__ flow, int& lt) {
    int sy = p / WW;
    int sx = p - sy * WW;
    int tx, ty;
    target_of(sx, sy, flow[p], flow[HWN + p], tx, ty);
    int tix = tx >> 7;          // / TDX
    int tiy = ty / TDY;         // / 27 (magic-mul)
    lt = (ty - tiy * TDY) * TDX + (tx - (tix << 7));   // < 3456, fits u16
    return tiy * NTX + tix;
}

// ---------------- binned path ----------------

__global__ void k_zero(unsigned* __restrict__ gcnt) {
    int i = blockIdx.x * blockDim.x + threadIdx.x;
    if (i < NTILES) gcnt[i] = 0u;
}

// Phase 1: per-tile source counts (LDS-aggregated, wave-leader global flush).
__global__ __launch_bounds__(256) void k_count(const float* __restrict__ flow,
                                               unsigned* __restrict__ gcnt) {
    __shared__ unsigned lc[NTILES];            // 9.6 KiB
    for (int i = threadIdx.x; i < NTILES; i += 256) lc[i] = 0u;
    __syncthreads();
    int lane = threadIdx.x & 63;
    int base = blockIdx.x * SLAB;
    for (int off = 0; off < SLAB; off += 256) {
        int p = base + off + threadIdx.x;
        int lt;
        int t = tile_of(p, flow, lt);
        u64 act = ~0ULL;
        while (act) {                           // wave-uniform loop
            int src = __builtin_ctzll(act);
            int t0 = __shfl(t, src);
            u64 eq = __ballot(t == t0) & act;
            if (lane == src) atomicAdd(&lc[t0], (unsigned)__builtin_popcountll(eq));
            act &= ~eq;
        }
    }
    __syncthreads();
    for (int i = threadIdx.x; i < NTILES; i += 256) {
        unsigned v = lc[i];
        if (v) atomicAdd(&gcnt[i], v);
    }
}

// Phase 2: exclusive prefix sum over 2400 tile counts (one block).
__global__ __launch_bounds__(256) void k_scan(const unsigned* __restrict__ gcnt,
                                              unsigned* __restrict__ goff,
                                              unsigned* __restrict__ gcur) {
    __shared__ unsigned part[256];
    int tid = threadIdx.x;
    unsigned loc[SCHUNK];
    unsigned s = 0u;
    for (int j = 0; j < SCHUNK; ++j) {
        int idx = tid * SCHUNK + j;
        loc[j] = s;
        if (idx < NTILES) s += gcnt[idx];
    }
    part[tid] = s;
    __syncthreads();
    for (int d = 1; d < 256; d <<= 1) {
        unsigned v = part[tid];
        unsigned w = (tid >= d) ? part[tid - d] : 0u;
        __syncthreads();
        part[tid] = v + w;
        __syncthreads();
    }
    unsigned base = (tid > 0) ? part[tid - 1] : 0u;
    for (int j = 0; j < SCHUNK; ++j) {
        int idx = tid * SCHUNK + j;
        if (idx < NTILES) {
            unsigned o = base + loc[j];
            goff[idx] = o;
            gcur[idx] = o;
        }
    }
    if (tid == 255) goff[NTILES] = part[255];   // == HWN
}

// Phase 3: scatter (depth,id) keys + local target idx into per-tile lists.
// Wave-aggregated cursor: one global atomicAdd per (wave, distinct tile).
__global__ __launch_bounds__(256) void k_scatter(const float* __restrict__ flow,
                                                 const float* __restrict__ depth,
                                                 unsigned* __restrict__ gcur,
                                                 u64* __restrict__ keys,
                                                 unsigned short* __restrict__ lts) {
    int lane = threadIdx.x & 63;
    int base = blockIdx.x * SLAB;
    for (int off = 0; off < SLAB; off += 256) {
        int p = base + off + threadIdx.x;
        int lt;
        int t = tile_of(p, flow, lt);
        u64 key = ((u64)__float_as_uint(depth[p]) << 32) | (unsigned)p;
        u64 act = ~0ULL;
        while (act) {
            int src = __builtin_ctzll(act);
            int t0 = __shfl(t, src);
            u64 eq = __ballot(t == t0) & act;
            int bs = 0;
            if (lane == src)
                bs = (int)atomicAdd(&gcur[t0], (unsigned)__builtin_popcountll(eq));
            bs = __shfl(bs, src);
            if ((eq >> lane) & 1ULL) {
                unsigned rank = (unsigned)__builtin_popcountll(eq & ((1ULL << lane) - 1ULL));
                unsigned slot = (unsigned)bs + rank;
                keys[slot] = key;
                lts[slot] = (unsigned short)lt;
            }
            act &= ~eq;
        }
    }
}

// Phase 4: per-tile LDS z-buffer from the exact source list, gather + write.
__global__ __launch_bounds__(1024) void k_tile(const float* __restrict__ obj,
                                               const u64* __restrict__ keys,
                                               const unsigned short* __restrict__ lts,
                                               const unsigned* __restrict__ goff,
                                               float* __restrict__ outf) {
    __shared__ u64 A[TPX];          // min (depth_bits, src_id)
    __shared__ u64 B[TPX];          // min (depth_bits, ~src_id)
    __shared__ unsigned cnt[TPX];   // 67.5 KiB total

    int bid = (blockIdx.x & 7) * (NTILES / 8) + (blockIdx.x >> 3);  // XCD swizzle (2400%8==0)
    int tix = bid % NTX;
    int tiy = bid / NTX;

    for (int i = threadIdx.x; i < TPX; i += 1024) {
        A[i] = ~0ULL;
        B[i] = ~0ULL;
        cnt[i] = 0u;
    }
    __syncthreads();

    unsigned s0 = goff[bid], s1 = goff[bid + 1];
    for (unsigned i = s0 + threadIdx.x; i < s1; i += 1024) {
        u64 k = keys[i];
        int lt = lts[i];
        atomicAdd(&cnt[lt], 1u);
        atomicMin(&A[lt], k);
        u64 kb = (k & 0xFFFFFFFF00000000ULL) | (u64)(unsigned)(~(unsigned)k);
        atomicMin(&B[lt], kb);
    }
    __syncthreads();

    int gx0 = tix * TDX;
    int gy0 = tiy * TDY;
    for (int i = threadIdx.x; i < TPX; i += 1024) {
        int lx = i & (TDX - 1);
        int ly = i >> 7;
        int g = (gy0 + ly) * WW + gx0 + lx;
        unsigned c = cnt[i];
        float o0 = 0.0f, o1 = 0.0f, o2 = 0.0f, v = 0.0f;
        if (c > 0u) {
            v = 1.0f;
            unsigned idA = (unsigned)A[i];      // smallest id at min depth
            unsigned idB = ~(unsigned)B[i];     // largest id at min depth
            o0 = obj[idA];
            o1 = obj[HWN + idA];
            o2 = obj[2 * HWN + idA];
            if (idB != idA) {                   // exact-depth tie -> max obj (ref semantics)
                o0 = fmaxf(o0, obj[idB]);
                o1 = fmaxf(o1, obj[HWN + idB]);
                o2 = fmaxf(o2, obj[2 * HWN + idB]);
            }
        }
        outf[g] = o0;
        outf[HWN + g] = o1;
        outf[2 * HWN + g] = o2;
        outf[3 * HWN + g] = v;
        outf[4 * HWN + g] = (float)c;
    }
}

// ---------------- fallback (Round-0, proven) path ----------------

__device__ __forceinline__ unsigned fmap(float f) {
    unsigned u = __float_as_uint(f);
    return (u & 0x80000000u) ? ~u : (u | 0x80000000u);
}
__device__ __forceinline__ float funmap(unsigned u) {
    return __uint_as_float((u & 0x80000000u) ? (u ^ 0x80000000u) : ~u);
}

__global__ void k_init(unsigned* __restrict__ out, unsigned* __restrict__ mind) {
    int stride = gridDim.x * blockDim.x;
    int i0 = blockIdx.x * blockDim.x + threadIdx.x;
    for (long p = i0; p < 5L * HWN; p += stride) out[p] = 0u;
    for (int p = i0; p < HWN; p += stride) mind[p] = 0xFFFFFFFFu;
}

__device__ __forceinline__ int target_idx(int p, const float* __restrict__ flow) {
    int y = p / WW;
    int x = p - y * WW;
    int tx, ty;
    target_of(x, y, flow[p], flow[HWN + p], tx, ty);
    return ty * WW + tx;
}

__global__ void k_pass1(const float* __restrict__ flow, const float* __restrict__ depth,
                        unsigned* __restrict__ cnt, unsigned* __restrict__ mind) {
    int p = blockIdx.x * blockDim.x + threadIdx.x;
    if (p >= HWN) return;
    int idx = target_idx(p, flow);
    atomicAdd(&cnt[idx], 1u);
    atomicMin(&mind[idx], __float_as_uint(depth[p]));
}

__global__ void k_pass2(const float* __restrict__ obj, const float* __restrict__ flow,
                        const float* __restrict__ depth, const unsigned* __restrict__ mind,
                        unsigned* __restrict__ acc) {
    int p = blockIdx.x * blockDim.x + threadIdx.x;
    if (p >= HWN) return;
    int idx = target_idx(p, flow);
    unsigned db = __float_as_uint(depth[p]);
    if (db <= mind[idx]) {
        atomicMax(&acc[idx], fmap(obj[p]));
        atomicMax(&acc[HWN + idx], fmap(obj[HWN + p]));
        atomicMax(&acc[2 * HWN + idx], fmap(obj[2 * HWN + p]));
    }
}

__global__ void k_final(unsigned* __restrict__ u, float* __restrict__ f) {
    int p = blockIdx.x * blockDim.x + threadIdx.x;
    if (p >= HWN) return;
    unsigned cu = u[4 * HWN + p];
    f[4 * HWN + p] = (float)cu;
    f[3 * HWN + p] = (cu > 0u) ? 1.0f : 0.0f;
    if (cu > 0u) {
        f[p] = funmap(u[p]);
        f[HWN + p] = funmap(u[HWN + p]);
        f[2 * HWN + p] = funmap(u[2 * HWN + p]);
    } else {
        f[p] = 0.0f;
        f[HWN + p] = 0.0f;
        f[2 * HWN + p] = 0.0f;
    }
}

extern "C" void kernel_launch(void* const* d_in, const int* in_sizes, int n_in,
                              void* d_out, int out_size, void* d_ws, size_t ws_size,
                              hipStream_t stream) {
    const float* obj   = (const float*)d_in[0];
    const float* flow  = (const float*)d_in[1];
    const float* depth = (const float*)d_in[2];
    float* outf = (float*)d_out;

    // ws layout: keys (HW*8) | lts (HW*2) | gcnt (2400*4) | goff (2401*4) | gcur (2400*4)
    u64* keys = (u64*)d_ws;
    unsigned short* lts = (unsigned short*)(keys + HWN);
    unsigned* gcnt = (unsigned*)((char*)d_ws + (size_t)HWN * 10u);
    unsigned* goff = gcnt + NTILES;
    unsigned* gcur = goff + NTILES + 1;
    const size_t needWS = (size_t)HWN * 10u + (size_t)(3 * NTILES + 1) * 4u; // ~83 MB

    if (ws_size >= needWS) {
        k_zero   <<<(NTILES + 255) / 256, 256, 0, stream>>>(gcnt);
        k_count  <<<NSLABS, 256, 0, stream>>>(flow, gcnt);
        k_scan   <<<1, 256, 0, stream>>>(gcnt, goff, gcur);
        k_scatter<<<NSLABS, 256, 0, stream>>>(flow, depth, gcur, keys, lts);
        k_tile   <<<NTILES, 1024, 0, stream>>>(obj, keys, lts, goff, outf);
    } else {
        const int T = 256;
        const int gridHW = (HWN + T - 1) / T;
        unsigned* outu = (unsigned*)d_out;
        unsigned* mind = (unsigned*)d_ws;   // 33.2 MB
        k_init <<<4096, T, 0, stream>>>(outu, mind);
        k_pass1<<<gridHW, T, 0, stream>>>(flow, depth, outu + 4L * HWN, mind);
        k_pass2<<<gridHW, T, 0, stream>>>(obj, flow, depth, mind, outu);
        k_final<<<gridHW, T, 0, stream>>>(outu, outf);
    }
}

// Round 4
// 296.060 us; speedup vs baseline: 4.1354x; 1.1567x over previous
//
#include <hip/hip_runtime.h>

typedef unsigned long long u64;

// obj (3,2160,3840) f32, flow (2,H,W) f32, depth (1,H,W) f32.
// Outputs concat: out (3,H,W), valid (1,H,W), collision (1,H,W) => 5*HW floats.
#define HH 2160
#define WW 3840
#define HWN (HH * WW)            // 8,294,400

// ---- exact binning geometry ----
#define TDX 128
#define TDY 27
#define NTX (WW / TDX)           // 30
#define NTY (HH / TDY)           // 80
#define NTILES (NTX * NTY)       // 2400
#define TPX (TDX * TDY)          // 3456 -> LDS 3456*20B = 69,120 B (2 blocks/CU)

#define SLAB 4096
#define NSLABS (HWN / SLAB)      // 2025 exactly
#define SCHUNK 10                // ceil(2400/256)

__device__ __forceinline__ void target_of(int sx, int sy, float fx, float fy,
                                          int& tx, int& ty) {
    float txf = fminf(fmaxf((float)sx + fx, 0.0f), (float)(WW - 1));
    float tyf = fminf(fmaxf((float)sy + fy, 0.0f), (float)(HH - 1));
    tx = (int)txf;   // >=0 -> truncation == floor, matches astype(int32)
    ty = (int)tyf;
}

__device__ __forceinline__ int tile_of(int p, const float* __restrict__ flow, int& lt) {
    int sy = p / WW;
    int sx = p - sy * WW;
    int tx, ty;
    target_of(sx, sy, flow[p], flow[HWN + p], tx, ty);
    int tix = tx >> 7;          // / TDX
    int tiy = ty / TDY;         // / 27 (magic-mul)
    lt = (ty - tiy * TDY) * TDX + (tx - (tix << 7));   // < 3456, fits u16
    return tiy * NTX + tix;
}

// Monotonic float <-> uint mapping (order-preserving for all non-NaN floats).
__device__ __forceinline__ unsigned fmap(float f) {
    unsigned u = __float_as_uint(f);
    return (u & 0x80000000u) ? ~u : (u | 0x80000000u);
}
__device__ __forceinline__ float funmap(unsigned u) {
    return __uint_as_float((u & 0x80000000u) ? (u ^ 0x80000000u) : ~u);
}

// ---------------- binned path ----------------

__global__ void k_zero(unsigned* __restrict__ gcnt) {
    int i = blockIdx.x * blockDim.x + threadIdx.x;
    if (i < NTILES) gcnt[i] = 0u;
}

// Phase 1: per-tile source counts (LDS-aggregated, wave-leader global flush).
__global__ __launch_bounds__(256) void k_count(const float* __restrict__ flow,
                                               unsigned* __restrict__ gcnt) {
    __shared__ unsigned lc[NTILES];            // 9.6 KiB
    for (int i = threadIdx.x; i < NTILES; i += 256) lc[i] = 0u;
    __syncthreads();
    int lane = threadIdx.x & 63;
    int base = blockIdx.x * SLAB;
    for (int off = 0; off < SLAB; off += 256) {
        int p = base + off + threadIdx.x;
        int lt;
        int t = tile_of(p, flow, lt);
        u64 act = ~0ULL;
        while (act) {                           // wave-uniform loop
            int src = __builtin_ctzll(act);
            int t0 = __shfl(t, src);
            u64 eq = __ballot(t == t0) & act;
            if (lane == src) atomicAdd(&lc[t0], (unsigned)__builtin_popcountll(eq));
            act &= ~eq;
        }
    }
    __syncthreads();
    for (int i = threadIdx.x; i < NTILES; i += 256) {
        unsigned v = lc[i];
        if (v) atomicAdd(&gcnt[i], v);
    }
}

// Phase 2: exclusive prefix sum over 2400 tile counts (one block).
__global__ __launch_bounds__(256) void k_scan(const unsigned* __restrict__ gcnt,
                                              unsigned* __restrict__ goff,
                                              unsigned* __restrict__ gcur) {
    __shared__ unsigned part[256];
    int tid = threadIdx.x;
    unsigned loc[SCHUNK];
    unsigned s = 0u;
    for (int j = 0; j < SCHUNK; ++j) {
        int idx = tid * SCHUNK + j;
        loc[j] = s;
        if (idx < NTILES) s += gcnt[idx];
    }
    part[tid] = s;
    __syncthreads();
    for (int d = 1; d < 256; d <<= 1) {
        unsigned v = part[tid];
        unsigned w = (tid >= d) ? part[tid - d] : 0u;
        __syncthreads();
        part[tid] = v + w;
        __syncthreads();
    }
    unsigned base = (tid > 0) ? part[tid - 1] : 0u;
    for (int j = 0; j < SCHUNK; ++j) {
        int idx = tid * SCHUNK + j;
        if (idx < NTILES) {
            unsigned o = base + loc[j];
            goff[idx] = o;
            gcur[idx] = o;
        }
    }
    if (tid == 255) goff[NTILES] = part[255];   // == HWN
}

// Phase 3: scatter per-entry payload (depth bits, local target, obj triplet) into
// per-tile lists. obj is read HERE, coalesced, so phase 4 never gathers randomly.
__global__ __launch_bounds__(256) void k_scatter(const float* __restrict__ flow,
                                                 const float* __restrict__ depth,
                                                 const float* __restrict__ obj,
                                                 unsigned* __restrict__ gcur,
                                                 unsigned* __restrict__ d32,
                                                 unsigned short* __restrict__ lt16,
                                                 float* __restrict__ ob0,
                                                 float* __restrict__ ob1,
                                                 float* __restrict__ ob2) {
    int lane = threadIdx.x & 63;
    int base = blockIdx.x * SLAB;
    for (int off = 0; off < SLAB; off += 256) {
        int p = base + off + threadIdx.x;
        int lt;
        int t = tile_of(p, flow, lt);
        unsigned db = __float_as_uint(depth[p]);   // depth>0 -> bits order-isomorphic
        float o0 = obj[p];
        float o1 = obj[HWN + p];
        float o2 = obj[2 * HWN + p];
        u64 act = ~0ULL;
        while (act) {
            int src = __builtin_ctzll(act);
            int t0 = __shfl(t, src);
            u64 eq = __ballot(t == t0) & act;
            int bs = 0;
            if (lane == src)
                bs = (int)atomicAdd(&gcur[t0], (unsigned)__builtin_popcountll(eq));
            bs = __shfl(bs, src);
            if ((eq >> lane) & 1ULL) {
                unsigned rank = (unsigned)__builtin_popcountll(eq & ((1ULL << lane) - 1ULL));
                unsigned slot = (unsigned)bs + rank;
                d32[slot] = db;
                lt16[slot] = (unsigned short)lt;
                ob0[slot] = o0;
                ob1[slot] = o1;
                ob2[slot] = o2;
            }
            act &= ~eq;
        }
    }
}

// Phase 4: per-tile LDS z-buffer. Pass A: min depth + count. Pass B: winner
// entries (d == min) atomicMax their fmapped obj -> exact reference tie
// semantics for any tie multiplicity. All global traffic is streaming.
__global__ __launch_bounds__(1024) void k_tile(const unsigned* __restrict__ d32,
                                               const unsigned short* __restrict__ lt16,
                                               const float* __restrict__ ob0,
                                               const float* __restrict__ ob1,
                                               const float* __restrict__ ob2,
                                               const unsigned* __restrict__ goff,
                                               float* __restrict__ outf) {
    __shared__ unsigned Ad[TPX];    // min depth bits
    __shared__ unsigned cnt[TPX];
    __shared__ unsigned m0[TPX];    // fmapped obj max per channel
    __shared__ unsigned m1[TPX];
    __shared__ unsigned m2[TPX];    // 69,120 B total

    int bid = (blockIdx.x & 7) * (NTILES / 8) + (blockIdx.x >> 3);  // XCD swizzle
    int tix = bid % NTX;
    int tiy = bid / NTX;

    for (int i = threadIdx.x; i < TPX; i += 1024) {
        Ad[i] = 0xFFFFFFFFu;
        cnt[i] = 0u;
        m0[i] = 0u;       // all real floats fmap to >= 0x00800000 > 0
        m1[i] = 0u;
        m2[i] = 0u;
    }
    __syncthreads();

    unsigned s0 = goff[bid], s1 = goff[bid + 1];
    for (unsigned i = s0 + threadIdx.x; i < s1; i += 1024) {
        unsigned d = d32[i];
        int lt = lt16[i];
        atomicAdd(&cnt[lt], 1u);
        atomicMin(&Ad[lt], d);
    }
    __syncthreads();

    for (unsigned i = s0 + threadIdx.x; i < s1; i += 1024) {   // L2-hot re-read
        unsigned d = d32[i];
        int lt = lt16[i];
        if (d == Ad[lt]) {            // winner: d <= min_d  <=>  d == min_d
            atomicMax(&m0[lt], fmap(ob0[i]));
            atomicMax(&m1[lt], fmap(ob1[i]));
            atomicMax(&m2[lt], fmap(ob2[i]));
        }
    }
    __syncthreads();

    int gx0 = tix * TDX;
    int gy0 = tiy * TDY;
    for (int i = threadIdx.x; i < TPX; i += 1024) {
        int lx = i & (TDX - 1);
        int ly = i >> 7;
        int g = (gy0 + ly) * WW + gx0 + lx;
        unsigned c = cnt[i];
        float o0 = 0.0f, o1 = 0.0f, o2 = 0.0f, v = 0.0f;
        if (c > 0u) {
            v = 1.0f;
            o0 = funmap(m0[i]);
            o1 = funmap(m1[i]);
            o2 = funmap(m2[i]);
        }
        outf[g] = o0;
        outf[HWN + g] = o1;
        outf[2 * HWN + g] = o2;
        outf[3 * HWN + g] = v;
        outf[4 * HWN + g] = (float)c;
    }
}

// ---------------- fallback (Round-0, proven) path ----------------

__global__ void k_init(unsigned* __restrict__ out, unsigned* __restrict__ mind) {
    int stride = gridDim.x * blockDim.x;
    int i0 = blockIdx.x * blockDim.x + threadIdx.x;
    for (long p = i0; p < 5L * HWN; p += stride) out[p] = 0u;
    for (int p = i0; p < HWN; p += stride) mind[p] = 0xFFFFFFFFu;
}

__device__ __forceinline__ int target_idx(int p, const float* __restrict__ flow) {
    int y = p / WW;
    int x = p - y * WW;
    int tx, ty;
    target_of(x, y, flow[p], flow[HWN + p], tx, ty);
    return ty * WW + tx;
}

__global__ void k_pass1(const float* __restrict__ flow, const float* __restrict__ depth,
                        unsigned* __restrict__ cnt, unsigned* __restrict__ mind) {
    int p = blockIdx.x * blockDim.x + threadIdx.x;
    if (p >= HWN) return;
    int idx = target_idx(p, flow);
    atomicAdd(&cnt[idx], 1u);
    atomicMin(&mind[idx], __float_as_uint(depth[p]));
}

__global__ void k_pass2(const float* __restrict__ obj, const float* __restrict__ flow,
                        const float* __restrict__ depth, const unsigned* __restrict__ mind,
                        unsigned* __restrict__ acc) {
    int p = blockIdx.x * blockDim.x + threadIdx.x;
    if (p >= HWN) return;
    int idx = target_idx(p, flow);
    unsigned db = __float_as_uint(depth[p]);
    if (db <= mind[idx]) {
        atomicMax(&acc[idx], fmap(obj[p]));
        atomicMax(&acc[HWN + idx], fmap(obj[HWN + p]));
        atomicMax(&acc[2 * HWN + idx], fmap(obj[2 * HWN + p]));
    }
}

__global__ void k_final(unsigned* __restrict__ u, float* __restrict__ f) {
    int p = blockIdx.x * blockDim.x + threadIdx.x;
    if (p >= HWN) return;
    unsigned cu = u[4 * HWN + p];
    f[4 * HWN + p] = (float)cu;
    f[3 * HWN + p] = (cu > 0u) ? 1.0f : 0.0f;
    if (cu > 0u) {
        f[p] = funmap(u[p]);
        f[HWN + p] = funmap(u[HWN + p]);
        f[2 * HWN + p] = funmap(u[2 * HWN + p]);
    } else {
        f[p] = 0.0f;
        f[HWN + p] = 0.0f;
        f[2 * HWN + p] = 0.0f;
    }
}

extern "C" void kernel_launch(void* const* d_in, const int* in_sizes, int n_in,
                              void* d_out, int out_size, void* d_ws, size_t ws_size,
                              hipStream_t stream) {
    const float* obj   = (const float*)d_in[0];
    const float* flow  = (const float*)d_in[1];
    const float* depth = (const float*)d_in[2];
    float* outf = (float*)d_out;

    // ws layout: ob0|ob1|ob2 (3*HW f32) | d32 (HW u32) | lt16 (HW u16)
    //            | gcnt (2400) | goff (2401) | gcur (2400)
    float* ob0 = (float*)d_ws;
    float* ob1 = ob0 + HWN;
    float* ob2 = ob1 + HWN;
    unsigned* d32 = (unsigned*)(ob2 + HWN);
    unsigned short* lt16 = (unsigned short*)(d32 + HWN);
    unsigned* gcnt = (unsigned*)(lt16 + HWN);
    unsigned* goff = gcnt + NTILES;
    unsigned* gcur = goff + NTILES + 1;
    const size_t needWS = (size_t)HWN * 18u + (size_t)(3 * NTILES + 1) * 4u; // ~149.3 MB

    if (ws_size >= needWS) {
        k_zero   <<<(NTILES + 255) / 256, 256, 0, stream>>>(gcnt);
        k_count  <<<NSLABS, 256, 0, stream>>>(flow, gcnt);
        k_scan   <<<1, 256, 0, stream>>>(gcnt, goff, gcur);
        k_scatter<<<NSLABS, 256, 0, stream>>>(flow, depth, obj, gcur,
                                              d32, lt16, ob0, ob1, ob2);
        k_tile   <<<NTILES, 1024, 0, stream>>>(d32, lt16, ob0, ob1, ob2, goff, outf);
    } else {
        const int T = 256;
        const int gridHW = (HWN + T - 1) / T;
        unsigned* outu = (unsigned*)d_out;
        unsigned* mind = (unsigned*)d_ws;   // 33.2 MB
        k_init <<<4096, T, 0, stream>>>(outu, mind);
        k_pass1<<<gridHW, T, 0, stream>>>(flow, depth, outu + 4L * HWN, mind);
        k_pass2<<<gridHW, T, 0, stream>>>(obj, flow, depth, mind, outu);
        k_final<<<gridHW, T, 0, stream>>>(outu, outf);
    }
}

// Round 5
// 194.102 us; speedup vs baseline: 6.3076x; 1.5253x over previous
//
#include <hip/hip_runtime.h>

typedef unsigned long long u64;

// obj (3,2160,3840) f32, flow (2,H,W) f32, depth (1,H,W) f32.
// Outputs concat: out (3,H,W), valid (1,H,W), collision (1,H,W) => 5*HW floats.
#define HH 2160
#define WW 3840
#define HWN (HH * WW)            // 8,294,400

// ---- exact binning geometry ----
#define TDX 128
#define TDY 27
#define NTX (WW / TDX)           // 30
#define NTY (HH / TDY)           // 80
#define NTILES (NTX * NTY)       // 2400
#define TPX (TDX * TDY)          // 3456 -> k_tile LDS 3456*20B = 69,120 B (2 blocks/CU)

// ---- 2-D source patches for hist/scatter ----
#define PCW 256
#define PCH 16
#define NPX (WW / PCW)           // 15
#define NPY (HH / PCH)           // 135
#define NPATCH (NPX * NPY)       // 2025
#define SCHUNK 10                // ceil(2400/256)

__device__ __forceinline__ void target_of(int sx, int sy, float fx, float fy,
                                          int& tx, int& ty) {
    float txf = fminf(fmaxf((float)sx + fx, 0.0f), (float)(WW - 1));
    float tyf = fminf(fmaxf((float)sy + fy, 0.0f), (float)(HH - 1));
    tx = (int)txf;   // >=0 -> truncation == floor, matches astype(int32)
    ty = (int)tyf;
}

// tile id + local target index from source pixel coords
__device__ __forceinline__ int tile_of_xy(int sx, int sy, float fx, float fy, int& lt) {
    int tx, ty;
    target_of(sx, sy, fx, fy, tx, ty);
    int tix = tx >> 7;          // / TDX
    int tiy = ty / TDY;         // / 27 (magic-mul)
    lt = (ty - tiy * TDY) * TDX + (tx - (tix << 7));   // < 3456, fits u16
    return tiy * NTX + tix;
}

// Monotonic float-bits <-> uint mapping (order-preserving for all non-NaN floats).
__device__ __forceinline__ unsigned fmapb(unsigned u) {
    return (u & 0x80000000u) ? ~u : (u | 0x80000000u);
}
__device__ __forceinline__ float funmap(unsigned u) {
    return __uint_as_float((u & 0x80000000u) ? (u ^ 0x80000000u) : ~u);
}

// ---------------- binned path ----------------

__global__ void k_zero(unsigned* __restrict__ gcnt) {
    int i = blockIdx.x * blockDim.x + threadIdx.x;
    if (i < NTILES) gcnt[i] = 0u;
}

// Phase 1: per-tile source counts. 2-D patch blocks, plain LDS histogram.
__global__ __launch_bounds__(256) void k_hist(const float* __restrict__ flow,
                                              unsigned* __restrict__ gcnt) {
    __shared__ unsigned lc[NTILES];            // 9.6 KiB
    for (int i = threadIdx.x; i < NTILES; i += 256) lc[i] = 0u;
    __syncthreads();
    int px0 = (blockIdx.x % NPX) * PCW;
    int py0 = (blockIdx.x / NPX) * PCH;
    for (int r = 0; r < PCH; ++r) {
        int sy = py0 + r;
        int sx = px0 + threadIdx.x;
        int p = sy * WW + sx;
        int lt;
        int t = tile_of_xy(sx, sy, flow[p], flow[HWN + p], lt);
        atomicAdd(&lc[t], 1u);
    }
    __syncthreads();
    for (int i = threadIdx.x; i < NTILES; i += 256) {
        unsigned v = lc[i];
        if (v) atomicAdd(&gcnt[i], v);
    }
}

// Phase 2: exclusive prefix sum over 2400 tile counts (one block).
__global__ __launch_bounds__(256) void k_scan(const unsigned* __restrict__ gcnt,
                                              unsigned* __restrict__ goff,
                                              unsigned* __restrict__ gcur) {
    __shared__ unsigned part[256];
    int tid = threadIdx.x;
    unsigned loc[SCHUNK];
    unsigned s = 0u;
    for (int j = 0; j < SCHUNK; ++j) {
        int idx = tid * SCHUNK + j;
        loc[j] = s;
        if (idx < NTILES) s += gcnt[idx];
    }
    part[tid] = s;
    __syncthreads();
    for (int d = 1; d < 256; d <<= 1) {
        unsigned v = part[tid];
        unsigned w = (tid >= d) ? part[tid - d] : 0u;
        __syncthreads();
        part[tid] = v + w;
        __syncthreads();
    }
    unsigned base = (tid > 0) ? part[tid - 1] : 0u;
    for (int j = 0; j < SCHUNK; ++j) {
        int idx = tid * SCHUNK + j;
        if (idx < NTILES) {
            unsigned o = base + loc[j];
            goff[idx] = o;
            gcur[idx] = o;
        }
    }
    if (tid == 255) goff[NTILES] = part[255];   // == HWN
}

// Phase 3: block-aggregated scatter. Pass 1 builds an LDS histogram and caches
// (tile,lt); one global atomicAdd per non-empty tile reserves a contiguous
// region; pass 2 ranks via LDS counters and writes ONE uint4 {depth_bits,
// fmap(o0), fmap(o1), fmap(o2)} + u16 lt per entry -> long coalesced runs.
__global__ __launch_bounds__(256) void k_scatter(const float* __restrict__ flow,
                                                 const float* __restrict__ depth,
                                                 const float* __restrict__ obj,
                                                 unsigned* __restrict__ gcur,
                                                 uint4* __restrict__ q,
                                                 unsigned short* __restrict__ lt16) {
    __shared__ unsigned lc[NTILES];     // 9.6 KiB (histogram, then rank counters)
    __shared__ unsigned lbase[NTILES];  // 9.6 KiB
    __shared__ unsigned tl[PCW * PCH];  // (t<<16)|lt, 16 KiB  -> 35.2 KiB total
    for (int i = threadIdx.x; i < NTILES; i += 256) lc[i] = 0u;
    __syncthreads();

    int px0 = (blockIdx.x % NPX) * PCW;
    int py0 = (blockIdx.x / NPX) * PCH;

    for (int r = 0; r < PCH; ++r) {
        int sy = py0 + r;
        int sx = px0 + threadIdx.x;
        int p = sy * WW + sx;
        int lt;
        int t = tile_of_xy(sx, sy, flow[p], flow[HWN + p], lt);
        tl[r * 256 + threadIdx.x] = ((unsigned)t << 16) | (unsigned)lt;
        atomicAdd(&lc[t], 1u);
    }
    __syncthreads();

    for (int i = threadIdx.x; i < NTILES; i += 256) {
        unsigned v = lc[i];
        lbase[i] = v ? atomicAdd(&gcur[i], v) : 0u;
        lc[i] = 0u;                      // reuse as rank counter
    }
    __syncthreads();

    for (int r = 0; r < PCH; ++r) {
        int sy = py0 + r;
        int sx = px0 + threadIdx.x;
        int p = sy * WW + sx;
        unsigned e = tl[r * 256 + threadIdx.x];
        unsigned t = e >> 16;
        unsigned lt = e & 0xFFFFu;
        unsigned rank = atomicAdd(&lc[t], 1u);
        unsigned slot = lbase[t] + rank;
        uint4 entry;
        entry.x = __float_as_uint(depth[p]);           // depth>0 -> order-isomorphic
        entry.y = fmapb(__float_as_uint(obj[p]));
        entry.z = fmapb(__float_as_uint(obj[HWN + p]));
        entry.w = fmapb(__float_as_uint(obj[2 * HWN + p]));
        q[slot] = entry;
        lt16[slot] = (unsigned short)lt;
    }
}

// Phase 4: per-tile LDS z-buffer. Pass A: min depth + count. Pass B (L2-hot):
// winner entries (d == min) atomicMax pre-fmapped obj -> exact reference tie
// semantics for any tie multiplicity. All global traffic is streaming.
__global__ __launch_bounds__(1024) void k_tile(const uint4* __restrict__ q,
                                               const unsigned short* __restrict__ lt16,
                                               const unsigned* __restrict__ goff,
                                               float* __restrict__ outf) {
    __shared__ unsigned Ad[TPX];    // min depth bits
    __shared__ unsigned cnt[TPX];
    __shared__ unsigned m0[TPX];    // fmapped obj max per channel
    __shared__ unsigned m1[TPX];
    __shared__ unsigned m2[TPX];    // 69,120 B total

    int bid = (blockIdx.x & 7) * (NTILES / 8) + (blockIdx.x >> 3);  // XCD swizzle
    int tix = bid % NTX;
    int tiy = bid / NTX;

    for (int i = threadIdx.x; i < TPX; i += 1024) {
        Ad[i] = 0xFFFFFFFFu;
        cnt[i] = 0u;
        m0[i] = 0u;       // all real floats fmap to >= 0x00800000 > 0
        m1[i] = 0u;
        m2[i] = 0u;
    }
    __syncthreads();

    unsigned s0 = goff[bid], s1 = goff[bid + 1];
    for (unsigned i = s0 + threadIdx.x; i < s1; i += 1024) {
        unsigned d = q[i].x;
        int lt = lt16[i];
        atomicAdd(&cnt[lt], 1u);
        atomicMin(&Ad[lt], d);
    }
    __syncthreads();

    for (unsigned i = s0 + threadIdx.x; i < s1; i += 1024) {   // L2-hot re-read
        uint4 e = q[i];
        int lt = lt16[i];
        if (e.x == Ad[lt]) {          // winner: d <= min_d  <=>  d == min_d
            atomicMax(&m0[lt], e.y);
            atomicMax(&m1[lt], e.z);
            atomicMax(&m2[lt], e.w);
        }
    }
    __syncthreads();

    int gx0 = tix * TDX;
    int gy0 = tiy * TDY;
    for (int i = threadIdx.x; i < TPX; i += 1024) {
        int lx = i & (TDX - 1);
        int ly = i >> 7;
        int g = (gy0 + ly) * WW + gx0 + lx;
        unsigned c = cnt[i];
        float o0 = 0.0f, o1 = 0.0f, o2 = 0.0f, v = 0.0f;
        if (c > 0u) {
            v = 1.0f;
            o0 = funmap(m0[i]);
            o1 = funmap(m1[i]);
            o2 = funmap(m2[i]);
        }
        outf[g] = o0;
        outf[HWN + g] = o1;
        outf[2 * HWN + g] = o2;
        outf[3 * HWN + g] = v;
        outf[4 * HWN + g] = (float)c;
    }
}

// ---------------- fallback (Round-0, proven) path ----------------

__device__ __forceinline__ unsigned fmap(float f) { return fmapb(__float_as_uint(f)); }

__global__ void k_init(unsigned* __restrict__ out, unsigned* __restrict__ mind) {
    int stride = gridDim.x * blockDim.x;
    int i0 = blockIdx.x * blockDim.x + threadIdx.x;
    for (long p = i0; p < 5L * HWN; p += stride) out[p] = 0u;
    for (int p = i0; p < HWN; p += stride) mind[p] = 0xFFFFFFFFu;
}

__device__ __forceinline__ int target_idx(int p, const float* __restrict__ flow) {
    int y = p / WW;
    int x = p - y * WW;
    int tx, ty;
    target_of(x, y, flow[p], flow[HWN + p], tx, ty);
    return ty * WW + tx;
}

__global__ void k_pass1(const float* __restrict__ flow, const float* __restrict__ depth,
                        unsigned* __restrict__ cnt, unsigned* __restrict__ mind) {
    int p = blockIdx.x * blockDim.x + threadIdx.x;
    if (p >= HWN) return;
    int idx = target_idx(p, flow);
    atomicAdd(&cnt[idx], 1u);
    atomicMin(&mind[idx], __float_as_uint(depth[p]));
}

__global__ void k_pass2(const float* __restrict__ obj, const float* __restrict__ flow,
                        const float* __restrict__ depth, const unsigned* __restrict__ mind,
                        unsigned* __restrict__ acc) {
    int p = blockIdx.x * blockDim.x + threadIdx.x;
    if (p >= HWN) return;
    int idx = target_idx(p, flow);
    unsigned db = __float_as_uint(depth[p]);
    if (db <= mind[idx]) {
        atomicMax(&acc[idx], fmap(obj[p]));
        atomicMax(&acc[HWN + idx], fmap(obj[HWN + p]));
        atomicMax(&acc[2 * HWN + idx], fmap(obj[2 * HWN + p]));
    }
}

__global__ void k_final(unsigned* __restrict__ u, float* __restrict__ f) {
    int p = blockIdx.x * blockDim.x + threadIdx.x;
    if (p >= HWN) return;
    unsigned cu = u[4 * HWN + p];
    f[4 * HWN + p] = (float)cu;
    f[3 * HWN + p] = (cu > 0u) ? 1.0f : 0.0f;
    if (cu > 0u) {
        f[p] = funmap(u[p]);
        f[HWN + p] = funmap(u[HWN + p]);
        f[2 * HWN + p] = funmap(u[2 * HWN + p]);
    } else {
        f[p] = 0.0f;
        f[HWN + p] = 0.0f;
        f[2 * HWN + p] = 0.0f;
    }
}

extern "C" void kernel_launch(void* const* d_in, const int* in_sizes, int n_in,
                              void* d_out, int out_size, void* d_ws, size_t ws_size,
                              hipStream_t stream) {
    const float* obj   = (const float*)d_in[0];
    const float* flow  = (const float*)d_in[1];
    const float* depth = (const float*)d_in[2];
    float* outf = (float*)d_out;

    // ws layout: q (HW uint4 = 132.7MB) | lt16 (HW u16 = 16.6MB)
    //            | gcnt (2400) | goff (2401) | gcur (2400)
    uint4* q = (uint4*)d_ws;
    unsigned short* lt16 = (unsigned short*)(q + HWN);
    unsigned* gcnt = (unsigned*)(lt16 + HWN);
    unsigned* goff = gcnt + NTILES;
    unsigned* gcur = goff + NTILES + 1;
    const size_t needWS = (size_t)HWN * 18u + (size_t)(3 * NTILES + 1) * 4u; // ~149.3 MB

    if (ws_size >= needWS) {
        k_zero   <<<(NTILES + 255) / 256, 256, 0, stream>>>(gcnt);
        k_hist   <<<NPATCH, 256, 0, stream>>>(flow, gcnt);
        k_scan   <<<1, 256, 0, stream>>>(gcnt, goff, gcur);
        k_scatter<<<NPATCH, 256, 0, stream>>>(flow, depth, obj, gcur, q, lt16);
        k_tile   <<<NTILES, 1024, 0, stream>>>(q, lt16, goff, outf);
    } else {
        const int T = 256;
        const int gridHW = (HWN + T - 1) / T;
        unsigned* outu = (unsigned*)d_out;
        unsigned* mind = (unsigned*)d_ws;   // 33.2 MB
        k_init <<<4096, T, 0, stream>>>(outu, mind);
        k_pass1<<<gridHW, T, 0, stream>>>(flow, depth, outu + 4L * HWN, mind);
        k_pass2<<<gridHW, T, 0, stream>>>(obj, flow, depth, mind, outu);
        k_final<<<gridHW, T, 0, stream>>>(outu, outf);
    }
}